// Round 5
// baseline (399.060 us; speedup 1.0000x reference)
//
#include <hip/hip_runtime.h>
#include <math.h>

#define N_NODES 16384
#define DIM 256
#define KNBR 16
#define D2 512

typedef __bf16 bf16x8 __attribute__((ext_vector_type(8)));
typedef float f32x4 __attribute__((ext_vector_type(4)));
typedef short short4v __attribute__((ext_vector_type(4)));
typedef short short8v __attribute__((ext_vector_type(8)));
typedef unsigned int u32;
typedef u32 u32x4 __attribute__((ext_vector_type(4)));
typedef unsigned short u16;

__device__ __forceinline__ u16 f2bf(float x) {
    u32 u = __builtin_bit_cast(u32, x);
    u = u + 0x7FFFu + ((u >> 16) & 1u);   // round-to-nearest-even
    return (u16)(u >> 16);
}
__device__ __forceinline__ float bf2f(u16 h) {
    u32 u = ((u32)h) << 16;
    return __builtin_bit_cast(float, u);
}

// XOR-swizzled LDS index (16B-unit swizzle) for a [rows][64] bf16 tile.
__device__ __forceinline__ int lds_swz(int row, int k) {
    return (row << 6) + ((((k >> 3) ^ (row & 7)) << 3) | (k & 7));
}

// ---------------------------------------------------------------------------
// pack_tables: XE[0:16384) = bf16(X) rows; XE[16384:16512) = bf16(Eemb) rows;
// WnbTh[n][k] = bf16(W_nb[k][n]); W1h[n][k] = bf16(W1[k][n]).
// ---------------------------------------------------------------------------
__global__ __launch_bounds__(256) void pack_tables(const float* __restrict__ X,
                                                   const float* __restrict__ Eemb,
                                                   const float* __restrict__ W_nb,
                                                   const float* __restrict__ W1,
                                                   u16* __restrict__ XE,
                                                   u16* __restrict__ WnbTh,
                                                   u16* __restrict__ W1h) {
    const int XN = N_NODES * DIM;            // 4194304
    const int EE = 128 * DIM;                // 32768
    const int WE = D2 * DIM;                 // 131072
    const int WE1 = 64 * DIM;                // 16384
    const int TOT = XN + EE + WE + WE1;
    for (int i = blockIdx.x * 256 + threadIdx.x; i < TOT; i += gridDim.x * 256) {
        if (i < XN) {
            XE[i] = f2bf(X[i]);
        } else if (i < XN + EE) {
            XE[i] = f2bf(Eemb[i - XN]);      // Eemb rows appended
        } else if (i < XN + EE + WE) {
            int j = i - XN - EE;             // j = n*512 + k
            int n = j >> 9, k = j & 511;
            WnbTh[j] = f2bf(W_nb[k * DIM + n]);
        } else {
            int j = i - XN - EE - WE;        // j = n*256 + k, n<64
            int n = j >> 8, k = j & 255;
            W1h[j] = f2bf(W1[k * 64 + n]);
        }
    }
}

// ---------------------------------------------------------------------------
// build_M: M = W_node @ attenW [512,256] as hi/lo bf16 split.
// b_node is softmax-invariant (constant over k) -> dropped.
// ---------------------------------------------------------------------------
__global__ __launch_bounds__(256) void build_M(const float* __restrict__ W_node,
                                               const float* __restrict__ attenW,
                                               u16* __restrict__ Mhi,
                                               u16* __restrict__ Mlo) {
    const int j = blockIdx.x;
    const int d = threadIdx.x;
    float acc = 0.f;
    for (int e = 0; e < DIM; ++e)
        acc = fmaf(W_node[j * DIM + e], attenW[e * DIM + d], acc);
    u16 h = f2bf(acc);
    Mhi[j * DIM + d] = h;
    Mlo[j * DIM + d] = f2bf(acc - bf2f(h));
}

// ---------------------------------------------------------------------------
// gemm_z: Zh[16384,512] bf16 = Xh @ (Mhi+Mlo)^T.  2 MFMA products (hh + hl).
// BM=128, BN=128, BK=64, 4 waves (2x2), mfma 16x16x32 bf16.
// ---------------------------------------------------------------------------
__global__ __launch_bounds__(256, 2) void gemm_z(const u16* __restrict__ Xh,
                                                 const u16* __restrict__ Mhi,
                                                 const u16* __restrict__ Mlo,
                                                 u16* __restrict__ Zh) {
    constexpr int BM = 128, BN = 128, BK = 64;
    constexpr int Kd = DIM, Nd = D2;
    __shared__ short Ah[BM * BK], Bh[BN * BK], Bl[BN * BK];
    const int tid = threadIdx.x;
    const int m0 = blockIdx.x * BM, n0 = blockIdx.y * BN;
    const int w = tid >> 6, lane = tid & 63;
    const int wr = (w >> 1) * 64, wc = (w & 1) * 64;
    const int lrow = lane & 15, lkg = lane >> 4;

    f32x4 acc[4][4] = {};

    for (int k0 = 0; k0 < Kd; k0 += BK) {
#pragma unroll
        for (int i = 0; i < 4; ++i) {
            int idx = i * 256 + tid;                 // 1024 short8 slots
            int r = idx >> 3, c8 = (idx & 7) << 3;
            int li = lds_swz(r, c8);
            *(short8v*)&Ah[li] = *(const short8v*)&Xh[(size_t)(m0 + r) * Kd + k0 + c8];
            *(short8v*)&Bh[li] = *(const short8v*)&Mhi[(size_t)(n0 + r) * Kd + k0 + c8];
            *(short8v*)&Bl[li] = *(const short8v*)&Mlo[(size_t)(n0 + r) * Kd + k0 + c8];
        }
        __syncthreads();
#pragma unroll
        for (int kk = 0; kk < 2; ++kk) {
            const int kof = kk * 32 + lkg * 8;
            bf16x8 a[4], bh[4], bl[4];
#pragma unroll
            for (int i = 0; i < 4; ++i) a[i] = *(const bf16x8*)&Ah[lds_swz(wr + i * 16 + lrow, kof)];
#pragma unroll
            for (int j = 0; j < 4; ++j) {
                bh[j] = *(const bf16x8*)&Bh[lds_swz(wc + j * 16 + lrow, kof)];
                bl[j] = *(const bf16x8*)&Bl[lds_swz(wc + j * 16 + lrow, kof)];
            }
#pragma unroll
            for (int i = 0; i < 4; ++i)
#pragma unroll
                for (int j = 0; j < 4; ++j) {
                    acc[i][j] = __builtin_amdgcn_mfma_f32_16x16x32_bf16(a[i], bh[j], acc[i][j], 0, 0, 0);
                    acc[i][j] = __builtin_amdgcn_mfma_f32_16x16x32_bf16(a[i], bl[j], acc[i][j], 0, 0, 0);
                }
        }
        __syncthreads();
    }
#pragma unroll
    for (int i = 0; i < 4; ++i)
#pragma unroll
        for (int j = 0; j < 4; ++j)
#pragma unroll
            for (int r = 0; r < 4; ++r) {
                int row = m0 + wr + i * 16 + lkg * 4 + r;
                int col = n0 + wc + j * 16 + lrow;
                Zh[(size_t)row * Nd + col] = f2bf(acc[i][j][r]);
            }
}

// ---------------------------------------------------------------------------
// gather_attn: ONE WAVE PER NODE, wave-independent: no LDS, no barriers.
// Indices via scalar (SGPR) loads; out-rows gathered once, stashed in 64
// VGPRs. In-side gathers issued AFTER softmax, fused into the aggregation
// loop (16 independent loads -> latency hidden by TLP, not VGPRs; R4's
// early in-stash cost 64 VGPRs -> occupancy 10% -> 2x slowdown).
// Logit reduce: in-register butterfly (lane l ends with logit[l&15]).
// REP (bf16) overwrites Zh row n in place.
// ---------------------------------------------------------------------------
__global__ __launch_bounds__(256, 4) void gather_attn(
    const u16* __restrict__ XE,   // [16512][256] bf16 (X rows, then Eemb rows)
    const int* __restrict__ in_idx, const int* __restrict__ in_edge,
    const float* __restrict__ in_mask, const int* __restrict__ out_idx,
    const int* __restrict__ out_edge, const float* __restrict__ out_mask,
    u16* __restrict__ Zh) {
    const int tid = threadIdx.x;
    const int w = tid >> 6, lane = tid & 63;
    const int n = blockIdx.x * 4 + w;
    const int nu = __builtin_amdgcn_readfirstlane(n);

    // scalar index loads (wave-uniform address -> s_load into SGPRs)
    int oi[KNBR], oe[KNBR], ii[KNBR], ie[KNBR];
#pragma unroll
    for (int k = 0; k < KNBR; ++k) {
        oi[k] = out_idx[nu * KNBR + k];
        oe[k] = out_edge[nu * KNBR + k];
        ii[k] = in_idx[nu * KNBR + k];
        ie[k] = in_edge[nu * KNBR + k];
    }
    // per-lane mask copies (lane l holds mask[l&15])
    const float im_v = in_mask[nu * KNBR + (lane & 15)];
    const float om_v = out_mask[nu * KNBR + (lane & 15)];

    // z slice: lane l holds concat dims [8l, 8l+8)
    float zr[8];
    {
        short8v zv = *(const short8v*)&Zh[(size_t)n * D2 + lane * 8];
#pragma unroll
        for (int c = 0; c < 8; ++c) zr[c] = bf2f((u16)zv[c]);
    }

    const u32 lofs = (u32)(lane & 31) * 16u;   // byte offset within row half
    const bool lo32 = (lane < 32);
    const char* XEb = (const char*)XE;

    // precompute gather byte-offsets
    u32 voff_out[KNBR], voff_in[KNBR];
#pragma unroll
    for (int k = 0; k < KNBR; ++k) {
        int ro = lo32 ? oi[k] : (N_NODES + oe[k]);
        int ri = lo32 ? ii[k] : (N_NODES + ie[k]);
        voff_out[k] = ((u32)ro << 9) + lofs;
        voff_in[k] = ((u32)ri << 9) + lofs;
    }

    // out-side gathers (stash lives across phases: 64 VGPRs)
    u32x4 stash[KNBR];
#pragma unroll
    for (int k = 0; k < KNBR; ++k)
        stash[k] = *(const u32x4*)(XEb + voff_out[k]);

    // logit partials
    float v[KNBR];
#pragma unroll
    for (int k = 0; k < KNBR; ++k) {
        short8v sv = __builtin_bit_cast(short8v, stash[k]);
        float q = 0.f;
#pragma unroll
        for (int c = 0; c < 8; ++c) q = fmaf(bf2f((u16)sv[c]), zr[c], q);
        v[k] = q;
    }

    // in-register butterfly: reduce 16 values over 64 lanes
    {
        const bool b0 = lane & 1;
#pragma unroll
        for (int i = 0; i < 8; ++i) {
            float keep = b0 ? v[2 * i + 1] : v[2 * i];
            float send = b0 ? v[2 * i] : v[2 * i + 1];
            v[i] = keep + __shfl_xor(send, 1);
        }
        const bool b1 = lane & 2;
#pragma unroll
        for (int i = 0; i < 4; ++i) {
            float keep = b1 ? v[2 * i + 1] : v[2 * i];
            float send = b1 ? v[2 * i] : v[2 * i + 1];
            v[i] = keep + __shfl_xor(send, 2);
        }
        const bool b2 = lane & 4;
#pragma unroll
        for (int i = 0; i < 2; ++i) {
            float keep = b2 ? v[2 * i + 1] : v[2 * i];
            float send = b2 ? v[2 * i] : v[2 * i + 1];
            v[i] = keep + __shfl_xor(send, 4);
        }
        const bool b3 = lane & 8;
        {
            float keep = b3 ? v[1] : v[0];
            float send = b3 ? v[0] : v[1];
            v[0] = keep + __shfl_xor(send, 8);
        }
    }
    float t = v[0];
    t += __shfl_xor(t, 16);
    t += __shfl_xor(t, 32);
    // t = logit[lane & 15] on every lane

    // softmax over the 16 k's (butterfly within 16-lane groups)
    float m = t;
#pragma unroll
    for (int d = 1; d < 16; d <<= 1) m = fmaxf(m, __shfl_xor(m, d));
    float e = __expf(t - m);
    float s = e;
#pragma unroll
    for (int d = 1; d < 16; d <<= 1) s += __shfl_xor(s, d);
    const float wt = e / s * om_v;   // lane l holds weight for k = l&15

    // aggregation: in-side gathered here (16 independent loads, pipelined)
    float acc[8] = {};
#pragma unroll
    for (int k = 0; k < KNBR; ++k) {
        u32x4 inv = *(const u32x4*)(XEb + voff_in[k]);
        short8v vin = __builtin_bit_cast(short8v, inv);
        short8v vout = __builtin_bit_cast(short8v, stash[k]);
        float imk = __shfl(im_v, k);
        float wtk = __shfl(wt, k);
#pragma unroll
        for (int c = 0; c < 8; ++c) {
            acc[c] = fmaf(imk, bf2f((u16)vin[c]), acc[c]);
            acc[c] = fmaf(wtk, bf2f((u16)vout[c]), acc[c]);
        }
    }
    short8v ov;
#pragma unroll
    for (int c = 0; c < 8; ++c) ov[c] = (short)f2bf(acc[c]);
    *(short8v*)&Zh[(size_t)n * D2 + lane * 8] = ov;   // REP overlays z row
}

// ---------------------------------------------------------------------------
// gemm_h: out[16384,256] f32 = REP @ WnbTh^T + X + 2*b_nb; also writes Hh bf16
// (for the MFMA MLP). A = REP rows in Zh, pitch 512 shorts.
// ---------------------------------------------------------------------------
__global__ __launch_bounds__(256, 3) void gemm_h(const u16* __restrict__ A,
                                                 const u16* __restrict__ B,
                                                 const float* __restrict__ X,
                                                 const float* __restrict__ b_nb,
                                                 float* __restrict__ out,
                                                 u16* __restrict__ Hh) {
    constexpr int BM = 128, BN = 128, BK = 64;
    constexpr int Kd = D2, Nd = DIM;
    __shared__ short Ah[BM * BK], Bh[BN * BK];
    const int tid = threadIdx.x;
    const int m0 = blockIdx.x * BM, n0 = blockIdx.y * BN;
    const int w = tid >> 6, lane = tid & 63;
    const int wr = (w >> 1) * 64, wc = (w & 1) * 64;
    const int lrow = lane & 15, lkg = lane >> 4;

    f32x4 acc[4][4] = {};

    for (int k0 = 0; k0 < Kd; k0 += BK) {
#pragma unroll
        for (int i = 0; i < 4; ++i) {
            int idx = i * 256 + tid;
            int r = idx >> 3, c8 = (idx & 7) << 3;
            int li = lds_swz(r, c8);
            *(short8v*)&Ah[li] = *(const short8v*)&A[(size_t)(m0 + r) * Kd + k0 + c8];
            *(short8v*)&Bh[li] = *(const short8v*)&B[(size_t)(n0 + r) * Kd + k0 + c8];
        }
        __syncthreads();
#pragma unroll
        for (int kk = 0; kk < 2; ++kk) {
            const int kof = kk * 32 + lkg * 8;
            bf16x8 a[4], b[4];
#pragma unroll
            for (int i = 0; i < 4; ++i) a[i] = *(const bf16x8*)&Ah[lds_swz(wr + i * 16 + lrow, kof)];
#pragma unroll
            for (int j = 0; j < 4; ++j) b[j] = *(const bf16x8*)&Bh[lds_swz(wc + j * 16 + lrow, kof)];
#pragma unroll
            for (int i = 0; i < 4; ++i)
#pragma unroll
                for (int j = 0; j < 4; ++j)
                    acc[i][j] = __builtin_amdgcn_mfma_f32_16x16x32_bf16(a[i], b[j], acc[i][j], 0, 0, 0);
        }
        __syncthreads();
    }
#pragma unroll
    for (int i = 0; i < 4; ++i)
#pragma unroll
        for (int j = 0; j < 4; ++j)
#pragma unroll
            for (int r = 0; r < 4; ++r) {
                int row = m0 + wr + i * 16 + lkg * 4 + r;
                int col = n0 + wc + j * 16 + lrow;
                size_t off = (size_t)row * Nd + col;
                float hv = acc[i][j][r] + X[off] + 2.0f * b_nb[col];
                out[off] = hv;
                Hh[off] = f2bf(hv);
            }
}

// ---------------------------------------------------------------------------
// mlp_mfma: per block of 128 rows: T = relu(Hh @ W1h^T + b1) [128,64] (MFMA),
// column-sum over rows, dot W2 -> 2 partials per block. Deterministic.
// ---------------------------------------------------------------------------
__global__ __launch_bounds__(256) void mlp_mfma(const u16* __restrict__ Hh,
                                                const u16* __restrict__ W1h,
                                                const float* __restrict__ b1,
                                                const float* __restrict__ W2,
                                                float* __restrict__ partials) {
    constexpr int BM = 128, BN = 64, BK = 64;
    constexpr int Kd = DIM;
    __shared__ short Ah[BM * BK], Bh[BN * BK];
    __shared__ float red[4][BN];
    const int tid = threadIdx.x;
    const int m0 = blockIdx.x * BM;
    const int w = tid >> 6, lane = tid & 63;
    const int wr = w * 32;
    const int lrow = lane & 15, lkg = lane >> 4;

    f32x4 acc[2][4] = {};

    for (int k0 = 0; k0 < Kd; k0 += BK) {
#pragma unroll
        for (int i = 0; i < 4; ++i) {
            int idx = i * 256 + tid;
            int r = idx >> 3, c8 = (idx & 7) << 3;
            *(short8v*)&Ah[lds_swz(r, c8)] =
                *(const short8v*)&Hh[(size_t)(m0 + r) * Kd + k0 + c8];
        }
#pragma unroll
        for (int i = 0; i < 2; ++i) {
            int idx = i * 256 + tid;
            if (idx < 512) {
                int r = idx >> 3, c8 = (idx & 7) << 3;
                *(short8v*)&Bh[lds_swz(r, c8)] =
                    *(const short8v*)&W1h[(size_t)r * Kd + k0 + c8];
            }
        }
        __syncthreads();
#pragma unroll
        for (int kk = 0; kk < 2; ++kk) {
            const int kof = kk * 32 + lkg * 8;
            bf16x8 a[2], b[4];
#pragma unroll
            for (int i = 0; i < 2; ++i) a[i] = *(const bf16x8*)&Ah[lds_swz(wr + i * 16 + lrow, kof)];
#pragma unroll
            for (int j = 0; j < 4; ++j) b[j] = *(const bf16x8*)&Bh[lds_swz(j * 16 + lrow, kof)];
#pragma unroll
            for (int i = 0; i < 2; ++i)
#pragma unroll
                for (int j = 0; j < 4; ++j)
                    acc[i][j] = __builtin_amdgcn_mfma_f32_16x16x32_bf16(a[i], b[j], acc[i][j], 0, 0, 0);
        }
        __syncthreads();
    }
    // relu(+b1) and column-sum over this wave's 32 rows
    float cs[4];
#pragma unroll
    for (int j = 0; j < 4; ++j) {
        const float bj = b1[j * 16 + lrow];
        float sv = 0.f;
#pragma unroll
        for (int i = 0; i < 2; ++i)
#pragma unroll
            for (int r = 0; r < 4; ++r) sv += fmaxf(acc[i][j][r] + bj, 0.f);
        cs[j] = sv;
    }
#pragma unroll
    for (int j = 0; j < 4; ++j) {
        cs[j] += __shfl_xor(cs[j], 16);
        cs[j] += __shfl_xor(cs[j], 32);
    }
    if (lkg == 0) {
#pragma unroll
        for (int j = 0; j < 4; ++j) red[w][j * 16 + lrow] = cs[j];
    }
    __syncthreads();
    if (tid < 64) {
        float t = red[0][tid] + red[1][tid] + red[2][tid] + red[3][tid];
        float h0 = t * W2[tid * 2 + 0];
        float h1 = t * W2[tid * 2 + 1];
#pragma unroll
        for (int off = 32; off > 0; off >>= 1) {
            h0 += __shfl_down(h0, off);
            h1 += __shfl_down(h1, off);
        }
        if (tid == 0) {
            partials[blockIdx.x * 2 + 0] = h0;
            partials[blockIdx.x * 2 + 1] = h1;
        }
    }
}

__global__ void finalize(const float* __restrict__ partials,
                         const float* __restrict__ b2, float* __restrict__ out) {
    const int l = threadIdx.x;
    float h0 = 0.f, h1 = 0.f;
    for (int i = l; i < 128; i += 64) {
        h0 += partials[2 * i + 0];
        h1 += partials[2 * i + 1];
    }
#pragma unroll
    for (int off = 32; off > 0; off >>= 1) {
        h0 += __shfl_down(h0, off);
        h1 += __shfl_down(h1, off);
    }
    if (l == 0) {
        h0 += (float)N_NODES * b2[0];
        h1 += (float)N_NODES * b2[1];
        const float m = fmaxf(h0, h1);
        const float e0 = __expf(h0 - m), e1 = __expf(h1 - m);
        out[(size_t)N_NODES * DIM + 0] = e0 / (e0 + e1);
        out[(size_t)N_NODES * DIM + 1] = e1 / (e0 + e1);
    }
}

extern "C" void kernel_launch(void* const* d_in, const int* in_sizes, int n_in,
                              void* d_out, int out_size, void* d_ws, size_t ws_size,
                              hipStream_t stream) {
    const float* X = (const float*)d_in[0];
    const int* in_idx = (const int*)d_in[1];
    const int* in_edge = (const int*)d_in[2];
    const float* in_mask = (const float*)d_in[3];
    const int* out_idx = (const int*)d_in[4];
    const int* out_edge = (const int*)d_in[5];
    const float* out_mask = (const float*)d_in[6];
    const float* Eemb = (const float*)d_in[7];
    const float* W_nb = (const float*)d_in[8];
    const float* b_nb = (const float*)d_in[9];
    const float* W_node = (const float*)d_in[10];
    // d_in[11] = b_node: softmax-invariant -> unused
    const float* attenW = (const float*)d_in[12];
    const float* W1 = (const float*)d_in[13];
    const float* b1 = (const float*)d_in[14];
    const float* W2 = (const float*)d_in[15];
    const float* b2 = (const float*)d_in[16];
    float* out = (float*)d_out;

    char* ws = (char*)d_ws;
    u16* Zh = (u16*)ws;                         // 16 MiB (REP overlays)
    u16* XE = (u16*)(ws + 16777216);            // 8.06 MiB
    u16* Mhi = (u16*)(ws + 25231360);           // 256 KiB
    u16* Mlo = (u16*)(ws + 25493504);           // 256 KiB
    u16* WnbTh = (u16*)(ws + 25755648);         // 256 KiB
    u16* W1h = (u16*)(ws + 26017792);           // 32 KiB
    u16* Hh = (u16*)(ws + 26050560);            // 8 MiB
    float* partials = (float*)(ws + 34439168);  // 1 KiB

    pack_tables<<<2048, 256, 0, stream>>>(X, Eemb, W_nb, W1, XE, WnbTh, W1h);
    build_M<<<512, 256, 0, stream>>>(W_node, attenW, Mhi, Mlo);
    gemm_z<<<dim3(128, 4), 256, 0, stream>>>(XE, Mhi, Mlo, Zh);
    gather_attn<<<N_NODES / 4, 256, 0, stream>>>(XE, in_idx, in_edge, in_mask,
                                                 out_idx, out_edge, out_mask, Zh);
    gemm_h<<<dim3(128, 2), 256, 0, stream>>>(Zh, WnbTh, X, b_nb, out, Hh);
    mlp_mfma<<<N_NODES / 128, 256, 0, stream>>>(Hh, W1h, b1, W2, partials);
    finalize<<<1, 64, 0, stream>>>(partials, b2, out);
}

// Round 6
// 200.210 us; speedup vs baseline: 1.9932x; 1.9932x over previous
//
#include <hip/hip_runtime.h>
#include <math.h>

#define N_NODES 16384
#define DIM 256
#define KNBR 16
#define D2 512

typedef __bf16 bf16x8 __attribute__((ext_vector_type(8)));
typedef float f32x4 __attribute__((ext_vector_type(4)));
typedef short short4v __attribute__((ext_vector_type(4)));
typedef short short8v __attribute__((ext_vector_type(8)));
typedef unsigned int u32;
typedef u32 u32x4 __attribute__((ext_vector_type(4)));
typedef unsigned short u16;

__device__ __forceinline__ u16 f2bf(float x) {
    u32 u = __builtin_bit_cast(u32, x);
    u = u + 0x7FFFu + ((u >> 16) & 1u);   // round-to-nearest-even
    return (u16)(u >> 16);
}
__device__ __forceinline__ float bf2f(u16 h) {
    u32 u = ((u32)h) << 16;
    return __builtin_bit_cast(float, u);
}

// XOR-swizzled LDS index (16B-unit swizzle) for a [rows][64] bf16 tile.
__device__ __forceinline__ int lds_swz(int row, int k) {
    return (row << 6) + ((((k >> 3) ^ (row & 7)) << 3) | (k & 7));
}

// ---------------------------------------------------------------------------
// pack_tables: XE[0:16384) = bf16(X) rows; XE[16384:16512) = bf16(Eemb) rows;
// WnbTh[n][k] = bf16(W_nb[k][n]); W1h[n][k] = bf16(W1[k][n]).
// ---------------------------------------------------------------------------
__global__ __launch_bounds__(256) void pack_tables(const float* __restrict__ X,
                                                   const float* __restrict__ Eemb,
                                                   const float* __restrict__ W_nb,
                                                   const float* __restrict__ W1,
                                                   u16* __restrict__ XE,
                                                   u16* __restrict__ WnbTh,
                                                   u16* __restrict__ W1h) {
    const int XN = N_NODES * DIM;            // 4194304
    const int EE = 128 * DIM;                // 32768
    const int WE = D2 * DIM;                 // 131072
    const int WE1 = 64 * DIM;                // 16384
    const int TOT = XN + EE + WE + WE1;
    for (int i = blockIdx.x * 256 + threadIdx.x; i < TOT; i += gridDim.x * 256) {
        if (i < XN) {
            XE[i] = f2bf(X[i]);
        } else if (i < XN + EE) {
            XE[i] = f2bf(Eemb[i - XN]);      // Eemb rows appended
        } else if (i < XN + EE + WE) {
            int j = i - XN - EE;             // j = n*512 + k
            int n = j >> 9, k = j & 511;
            WnbTh[j] = f2bf(W_nb[k * DIM + n]);
        } else {
            int j = i - XN - EE - WE;        // j = n*256 + k, n<64
            int n = j >> 8, k = j & 255;
            W1h[j] = f2bf(W1[k * 64 + n]);
        }
    }
}

// ---------------------------------------------------------------------------
// build_M: M = W_node @ attenW [512,256] as hi/lo bf16 split.
// b_node is softmax-invariant (constant over k) -> dropped.
// ---------------------------------------------------------------------------
__global__ __launch_bounds__(256) void build_M(const float* __restrict__ W_node,
                                               const float* __restrict__ attenW,
                                               u16* __restrict__ Mhi,
                                               u16* __restrict__ Mlo) {
    const int j = blockIdx.x;
    const int d = threadIdx.x;
    float acc = 0.f;
    for (int e = 0; e < DIM; ++e)
        acc = fmaf(W_node[j * DIM + e], attenW[e * DIM + d], acc);
    u16 h = f2bf(acc);
    Mhi[j * DIM + d] = h;
    Mlo[j * DIM + d] = f2bf(acc - bf2f(h));
}

// ---------------------------------------------------------------------------
// gemm_z: Zh[16384,512] bf16 = Xh @ (Mhi+Mlo)^T.  2 MFMA products (hh + hl).
// BM=128, BN=128, BK=64, 4 waves (2x2), mfma 16x16x32 bf16.
// ---------------------------------------------------------------------------
__global__ __launch_bounds__(256, 2) void gemm_z(const u16* __restrict__ Xh,
                                                 const u16* __restrict__ Mhi,
                                                 const u16* __restrict__ Mlo,
                                                 u16* __restrict__ Zh) {
    constexpr int BM = 128, BN = 128, BK = 64;
    constexpr int Kd = DIM, Nd = D2;
    __shared__ short Ah[BM * BK], Bh[BN * BK], Bl[BN * BK];
    const int tid = threadIdx.x;
    const int m0 = blockIdx.x * BM, n0 = blockIdx.y * BN;
    const int w = tid >> 6, lane = tid & 63;
    const int wr = (w >> 1) * 64, wc = (w & 1) * 64;
    const int lrow = lane & 15, lkg = lane >> 4;

    f32x4 acc[4][4] = {};

    for (int k0 = 0; k0 < Kd; k0 += BK) {
#pragma unroll
        for (int i = 0; i < 4; ++i) {
            int idx = i * 256 + tid;                 // 1024 short8 slots
            int r = idx >> 3, c8 = (idx & 7) << 3;
            int li = lds_swz(r, c8);
            *(short8v*)&Ah[li] = *(const short8v*)&Xh[(size_t)(m0 + r) * Kd + k0 + c8];
            *(short8v*)&Bh[li] = *(const short8v*)&Mhi[(size_t)(n0 + r) * Kd + k0 + c8];
            *(short8v*)&Bl[li] = *(const short8v*)&Mlo[(size_t)(n0 + r) * Kd + k0 + c8];
        }
        __syncthreads();
#pragma unroll
        for (int kk = 0; kk < 2; ++kk) {
            const int kof = kk * 32 + lkg * 8;
            bf16x8 a[4], bh[4], bl[4];
#pragma unroll
            for (int i = 0; i < 4; ++i) a[i] = *(const bf16x8*)&Ah[lds_swz(wr + i * 16 + lrow, kof)];
#pragma unroll
            for (int j = 0; j < 4; ++j) {
                bh[j] = *(const bf16x8*)&Bh[lds_swz(wc + j * 16 + lrow, kof)];
                bl[j] = *(const bf16x8*)&Bl[lds_swz(wc + j * 16 + lrow, kof)];
            }
#pragma unroll
            for (int i = 0; i < 4; ++i)
#pragma unroll
                for (int j = 0; j < 4; ++j) {
                    acc[i][j] = __builtin_amdgcn_mfma_f32_16x16x32_bf16(a[i], bh[j], acc[i][j], 0, 0, 0);
                    acc[i][j] = __builtin_amdgcn_mfma_f32_16x16x32_bf16(a[i], bl[j], acc[i][j], 0, 0, 0);
                }
        }
        __syncthreads();
    }
#pragma unroll
    for (int i = 0; i < 4; ++i)
#pragma unroll
        for (int j = 0; j < 4; ++j)
#pragma unroll
            for (int r = 0; r < 4; ++r) {
                int row = m0 + wr + i * 16 + lkg * 4 + r;
                int col = n0 + wc + j * 16 + lrow;
                Zh[(size_t)row * Nd + col] = f2bf(acc[i][j][r]);
            }
}

// ---------------------------------------------------------------------------
// gather_attn: ONE WAVE PER NODE, wave-independent: no LDS, no barriers,
// NO persistent stash (R5 lesson: 64-reg stash + bounds cap => scratch
// spills, WRITE_SIZE 716MB). XE is 8.45MB = L2/L3-resident, so the out-rows
// are simply re-gathered in the aggregation phase; offsets recomputed inline
// from SGPR indices. Target: <=64 live VGPRs naturally -> high occupancy.
// Logit reduce: in-register butterfly (lane l ends with logit[l&15]).
// REP (bf16) overwrites Zh row n in place.
// ---------------------------------------------------------------------------
__global__ __launch_bounds__(256) void gather_attn(
    const u16* __restrict__ XE,   // [16512][256] bf16 (X rows, then Eemb rows)
    const int* __restrict__ in_idx, const int* __restrict__ in_edge,
    const float* __restrict__ in_mask, const int* __restrict__ out_idx,
    const int* __restrict__ out_edge, const float* __restrict__ out_mask,
    u16* __restrict__ Zh) {
    const int tid = threadIdx.x;
    const int w = tid >> 6, lane = tid & 63;
    const int n = blockIdx.x * 4 + w;
    const int nu = __builtin_amdgcn_readfirstlane(n);

    // scalar index loads (wave-uniform address -> s_load into SGPRs)
    int oi[KNBR], noe[KNBR], ii[KNBR], nie[KNBR];
#pragma unroll
    for (int k = 0; k < KNBR; ++k) {
        oi[k] = out_idx[nu * KNBR + k];
        noe[k] = N_NODES + out_edge[nu * KNBR + k];
        ii[k] = in_idx[nu * KNBR + k];
        nie[k] = N_NODES + in_edge[nu * KNBR + k];
    }
    // per-lane mask copies (lane l holds mask[l&15])
    const float im_v = in_mask[nu * KNBR + (lane & 15)];
    const float om_v = out_mask[nu * KNBR + (lane & 15)];

    // z slice: lane l holds concat dims [8l, 8l+8)
    float zr[8];
    {
        short8v zv = *(const short8v*)&Zh[(size_t)n * D2 + lane * 8];
#pragma unroll
        for (int c = 0; c < 8; ++c) zr[c] = bf2f((u16)zv[c]);
    }

    const u32 lofs = (u32)(lane & 31) * 16u;   // byte offset within row half
    const bool lo32 = (lane < 32);
    const char* XEb = (const char*)XE;

    // Phase B: logit partials (out-rows loaded, consumed, NOT kept)
    float v[KNBR];
#pragma unroll 8
    for (int k = 0; k < KNBR; ++k) {
        int ro = lo32 ? oi[k] : noe[k];
        u32x4 vo = *(const u32x4*)(XEb + (((u32)ro << 9) + lofs));
        short8v sv = __builtin_bit_cast(short8v, vo);
        float q = 0.f;
#pragma unroll
        for (int c = 0; c < 8; ++c) q = fmaf(bf2f((u16)sv[c]), zr[c], q);
        v[k] = q;
    }

    // in-register butterfly: reduce 16 values over 64 lanes
    {
        const bool b0 = lane & 1;
#pragma unroll
        for (int i = 0; i < 8; ++i) {
            float keep = b0 ? v[2 * i + 1] : v[2 * i];
            float send = b0 ? v[2 * i] : v[2 * i + 1];
            v[i] = keep + __shfl_xor(send, 1);
        }
        const bool b1 = lane & 2;
#pragma unroll
        for (int i = 0; i < 4; ++i) {
            float keep = b1 ? v[2 * i + 1] : v[2 * i];
            float send = b1 ? v[2 * i] : v[2 * i + 1];
            v[i] = keep + __shfl_xor(send, 2);
        }
        const bool b2 = lane & 4;
#pragma unroll
        for (int i = 0; i < 2; ++i) {
            float keep = b2 ? v[2 * i + 1] : v[2 * i];
            float send = b2 ? v[2 * i] : v[2 * i + 1];
            v[i] = keep + __shfl_xor(send, 4);
        }
        const bool b3 = lane & 8;
        {
            float keep = b3 ? v[1] : v[0];
            float send = b3 ? v[0] : v[1];
            v[0] = keep + __shfl_xor(send, 8);
        }
    }
    float t = v[0];
    t += __shfl_xor(t, 16);
    t += __shfl_xor(t, 32);
    // t = logit[lane & 15] on every lane

    // softmax over the 16 k's (butterfly within 16-lane groups)
    float m = t;
#pragma unroll
    for (int d = 1; d < 16; d <<= 1) m = fmaxf(m, __shfl_xor(m, d));
    float e = __expf(t - m);
    float s = e;
#pragma unroll
    for (int d = 1; d < 16; d <<= 1) s += __shfl_xor(s, d);
    const float wt = e / s * om_v;   // lane l holds weight for k = l&15

    // aggregation: re-gather out-rows (L2-hit) + in-rows, 4-deep pipeline
    float acc[8] = {};
#pragma unroll 4
    for (int k = 0; k < KNBR; ++k) {
        int ro = lo32 ? oi[k] : noe[k];
        int ri = lo32 ? ii[k] : nie[k];
        u32x4 vo4 = *(const u32x4*)(XEb + (((u32)ro << 9) + lofs));
        u32x4 vi4 = *(const u32x4*)(XEb + (((u32)ri << 9) + lofs));
        short8v vout = __builtin_bit_cast(short8v, vo4);
        short8v vin = __builtin_bit_cast(short8v, vi4);
        float imk = __shfl(im_v, k);
        float wtk = __shfl(wt, k);
#pragma unroll
        for (int c = 0; c < 8; ++c) {
            acc[c] = fmaf(imk, bf2f((u16)vin[c]), acc[c]);
            acc[c] = fmaf(wtk, bf2f((u16)vout[c]), acc[c]);
        }
    }
    short8v ov;
#pragma unroll
    for (int c = 0; c < 8; ++c) ov[c] = (short)f2bf(acc[c]);
    *(short8v*)&Zh[(size_t)n * D2 + lane * 8] = ov;   // REP overlays z row
}

// ---------------------------------------------------------------------------
// gemm_h: out[16384,256] f32 = REP @ WnbTh^T + X + 2*b_nb; also writes Hh bf16
// (for the MFMA MLP). A = REP rows in Zh, pitch 512 shorts.
// ---------------------------------------------------------------------------
__global__ __launch_bounds__(256, 3) void gemm_h(const u16* __restrict__ A,
                                                 const u16* __restrict__ B,
                                                 const float* __restrict__ X,
                                                 const float* __restrict__ b_nb,
                                                 float* __restrict__ out,
                                                 u16* __restrict__ Hh) {
    constexpr int BM = 128, BN = 128, BK = 64;
    constexpr int Kd = D2, Nd = DIM;
    __shared__ short Ah[BM * BK], Bh[BN * BK];
    const int tid = threadIdx.x;
    const int m0 = blockIdx.x * BM, n0 = blockIdx.y * BN;
    const int w = tid >> 6, lane = tid & 63;
    const int wr = (w >> 1) * 64, wc = (w & 1) * 64;
    const int lrow = lane & 15, lkg = lane >> 4;

    f32x4 acc[4][4] = {};

    for (int k0 = 0; k0 < Kd; k0 += BK) {
#pragma unroll
        for (int i = 0; i < 4; ++i) {
            int idx = i * 256 + tid;
            int r = idx >> 3, c8 = (idx & 7) << 3;
            int li = lds_swz(r, c8);
            *(short8v*)&Ah[li] = *(const short8v*)&A[(size_t)(m0 + r) * Kd + k0 + c8];
            *(short8v*)&Bh[li] = *(const short8v*)&B[(size_t)(n0 + r) * Kd + k0 + c8];
        }
        __syncthreads();
#pragma unroll
        for (int kk = 0; kk < 2; ++kk) {
            const int kof = kk * 32 + lkg * 8;
            bf16x8 a[4], b[4];
#pragma unroll
            for (int i = 0; i < 4; ++i) a[i] = *(const bf16x8*)&Ah[lds_swz(wr + i * 16 + lrow, kof)];
#pragma unroll
            for (int j = 0; j < 4; ++j) b[j] = *(const bf16x8*)&Bh[lds_swz(wc + j * 16 + lrow, kof)];
#pragma unroll
            for (int i = 0; i < 4; ++i)
#pragma unroll
                for (int j = 0; j < 4; ++j)
                    acc[i][j] = __builtin_amdgcn_mfma_f32_16x16x32_bf16(a[i], b[j], acc[i][j], 0, 0, 0);
        }
        __syncthreads();
    }
#pragma unroll
    for (int i = 0; i < 4; ++i)
#pragma unroll
        for (int j = 0; j < 4; ++j)
#pragma unroll
            for (int r = 0; r < 4; ++r) {
                int row = m0 + wr + i * 16 + lkg * 4 + r;
                int col = n0 + wc + j * 16 + lrow;
                size_t off = (size_t)row * Nd + col;
                float hv = acc[i][j][r] + X[off] + 2.0f * b_nb[col];
                out[off] = hv;
                Hh[off] = f2bf(hv);
            }
}

// ---------------------------------------------------------------------------
// mlp_mfma: per block of 128 rows: T = relu(Hh @ W1h^T + b1) [128,64] (MFMA),
// column-sum over rows, dot W2 -> 2 partials per block. Deterministic.
// ---------------------------------------------------------------------------
__global__ __launch_bounds__(256) void mlp_mfma(const u16* __restrict__ Hh,
                                                const u16* __restrict__ W1h,
                                                const float* __restrict__ b1,
                                                const float* __restrict__ W2,
                                                float* __restrict__ partials) {
    constexpr int BM = 128, BN = 64, BK = 64;
    constexpr int Kd = DIM;
    __shared__ short Ah[BM * BK], Bh[BN * BK];
    __shared__ float red[4][BN];
    const int tid = threadIdx.x;
    const int m0 = blockIdx.x * BM;
    const int w = tid >> 6, lane = tid & 63;
    const int wr = w * 32;
    const int lrow = lane & 15, lkg = lane >> 4;

    f32x4 acc[2][4] = {};

    for (int k0 = 0; k0 < Kd; k0 += BK) {
#pragma unroll
        for (int i = 0; i < 4; ++i) {
            int idx = i * 256 + tid;
            int r = idx >> 3, c8 = (idx & 7) << 3;
            *(short8v*)&Ah[lds_swz(r, c8)] =
                *(const short8v*)&Hh[(size_t)(m0 + r) * Kd + k0 + c8];
        }
#pragma unroll
        for (int i = 0; i < 2; ++i) {
            int idx = i * 256 + tid;
            if (idx < 512) {
                int r = idx >> 3, c8 = (idx & 7) << 3;
                *(short8v*)&Bh[lds_swz(r, c8)] =
                    *(const short8v*)&W1h[(size_t)r * Kd + k0 + c8];
            }
        }
        __syncthreads();
#pragma unroll
        for (int kk = 0; kk < 2; ++kk) {
            const int kof = kk * 32 + lkg * 8;
            bf16x8 a[2], b[4];
#pragma unroll
            for (int i = 0; i < 2; ++i) a[i] = *(const bf16x8*)&Ah[lds_swz(wr + i * 16 + lrow, kof)];
#pragma unroll
            for (int j = 0; j < 4; ++j) b[j] = *(const bf16x8*)&Bh[lds_swz(j * 16 + lrow, kof)];
#pragma unroll
            for (int i = 0; i < 2; ++i)
#pragma unroll
                for (int j = 0; j < 4; ++j)
                    acc[i][j] = __builtin_amdgcn_mfma_f32_16x16x32_bf16(a[i], b[j], acc[i][j], 0, 0, 0);
        }
        __syncthreads();
    }
    // relu(+b1) and column-sum over this wave's 32 rows
    float cs[4];
#pragma unroll
    for (int j = 0; j < 4; ++j) {
        const float bj = b1[j * 16 + lrow];
        float sv = 0.f;
#pragma unroll
        for (int i = 0; i < 2; ++i)
#pragma unroll
            for (int r = 0; r < 4; ++r) sv += fmaxf(acc[i][j][r] + bj, 0.f);
        cs[j] = sv;
    }
#pragma unroll
    for (int j = 0; j < 4; ++j) {
        cs[j] += __shfl_xor(cs[j], 16);
        cs[j] += __shfl_xor(cs[j], 32);
    }
    if (lkg == 0) {
#pragma unroll
        for (int j = 0; j < 4; ++j) red[w][j * 16 + lrow] = cs[j];
    }
    __syncthreads();
    if (tid < 64) {
        float t = red[0][tid] + red[1][tid] + red[2][tid] + red[3][tid];
        float h0 = t * W2[tid * 2 + 0];
        float h1 = t * W2[tid * 2 + 1];
#pragma unroll
        for (int off = 32; off > 0; off >>= 1) {
            h0 += __shfl_down(h0, off);
            h1 += __shfl_down(h1, off);
        }
        if (tid == 0) {
            partials[blockIdx.x * 2 + 0] = h0;
            partials[blockIdx.x * 2 + 1] = h1;
        }
    }
}

__global__ void finalize(const float* __restrict__ partials,
                         const float* __restrict__ b2, float* __restrict__ out) {
    const int l = threadIdx.x;
    float h0 = 0.f, h1 = 0.f;
    for (int i = l; i < 128; i += 64) {
        h0 += partials[2 * i + 0];
        h1 += partials[2 * i + 1];
    }
#pragma unroll
    for (int off = 32; off > 0; off >>= 1) {
        h0 += __shfl_down(h0, off);
        h1 += __shfl_down(h1, off);
    }
    if (l == 0) {
        h0 += (float)N_NODES * b2[0];
        h1 += (float)N_NODES * b2[1];
        const float m = fmaxf(h0, h1);
        const float e0 = __expf(h0 - m), e1 = __expf(h1 - m);
        out[(size_t)N_NODES * DIM + 0] = e0 / (e0 + e1);
        out[(size_t)N_NODES * DIM + 1] = e1 / (e0 + e1);
    }
}

extern "C" void kernel_launch(void* const* d_in, const int* in_sizes, int n_in,
                              void* d_out, int out_size, void* d_ws, size_t ws_size,
                              hipStream_t stream) {
    const float* X = (const float*)d_in[0];
    const int* in_idx = (const int*)d_in[1];
    const int* in_edge = (const int*)d_in[2];
    const float* in_mask = (const float*)d_in[3];
    const int* out_idx = (const int*)d_in[4];
    const int* out_edge = (const int*)d_in[5];
    const float* out_mask = (const float*)d_in[6];
    const float* Eemb = (const float*)d_in[7];
    const float* W_nb = (const float*)d_in[8];
    const float* b_nb = (const float*)d_in[9];
    const float* W_node = (const float*)d_in[10];
    // d_in[11] = b_node: softmax-invariant -> unused
    const float* attenW = (const float*)d_in[12];
    const float* W1 = (const float*)d_in[13];
    const float* b1 = (const float*)d_in[14];
    const float* W2 = (const float*)d_in[15];
    const float* b2 = (const float*)d_in[16];
    float* out = (float*)d_out;

    char* ws = (char*)d_ws;
    u16* Zh = (u16*)ws;                         // 16 MiB (REP overlays)
    u16* XE = (u16*)(ws + 16777216);            // 8.06 MiB
    u16* Mhi = (u16*)(ws + 25231360);           // 256 KiB
    u16* Mlo = (u16*)(ws + 25493504);           // 256 KiB
    u16* WnbTh = (u16*)(ws + 25755648);         // 256 KiB
    u16* W1h = (u16*)(ws + 26017792);           // 32 KiB
    u16* Hh = (u16*)(ws + 26050560);            // 8 MiB
    float* partials = (float*)(ws + 34439168);  // 1 KiB

    pack_tables<<<2048, 256, 0, stream>>>(X, Eemb, W_nb, W1, XE, WnbTh, W1h);
    build_M<<<512, 256, 0, stream>>>(W_node, attenW, Mhi, Mlo);
    gemm_z<<<dim3(128, 4), 256, 0, stream>>>(XE, Mhi, Mlo, Zh);
    gather_attn<<<N_NODES / 4, 256, 0, stream>>>(XE, in_idx, in_edge, in_mask,
                                                 out_idx, out_edge, out_mask, Zh);
    gemm_h<<<dim3(128, 2), 256, 0, stream>>>(Zh, WnbTh, X, b_nb, out, Hh);
    mlp_mfma<<<N_NODES / 128, 256, 0, stream>>>(Hh, W1h, b1, W2, partials);
    finalize<<<1, 64, 0, stream>>>(partials, b2, out);
}

// Round 7
// 131.993 us; speedup vs baseline: 3.0233x; 1.5168x over previous
//
#include <hip/hip_runtime.h>
#include <math.h>

#define N_NODES 16384
#define DIM 256
#define KNBR 16
#define D2 512

typedef __bf16 bf16x8 __attribute__((ext_vector_type(8)));
typedef float f32x4 __attribute__((ext_vector_type(4)));
typedef short short4v __attribute__((ext_vector_type(4)));
typedef short short8v __attribute__((ext_vector_type(8)));
typedef unsigned int u32;
typedef u32 u32x4 __attribute__((ext_vector_type(4)));
typedef unsigned short u16;

__device__ __forceinline__ u16 f2bf(float x) {
    u32 u = __builtin_bit_cast(u32, x);
    u = u + 0x7FFFu + ((u >> 16) & 1u);   // round-to-nearest-even
    return (u16)(u >> 16);
}
__device__ __forceinline__ float bf2f(u16 h) {
    u32 u = ((u32)h) << 16;
    return __builtin_bit_cast(float, u);
}

// XOR-swizzled LDS index (16B-unit swizzle) for a [rows][64] bf16 tile.
__device__ __forceinline__ int lds_swz(int row, int k) {
    return (row << 6) + ((((k >> 3) ^ (row & 7)) << 3) | (k & 7));
}

// ---------------------------------------------------------------------------
// pack_tables: XE[0:16384) = bf16(X) rows; XE[16384:16512) = bf16(Eemb) rows;
// WnbTh[n][k] = bf16(W_nb[k][n]); W1h[n][k] = bf16(W1[k][n]).
// ---------------------------------------------------------------------------
__global__ __launch_bounds__(256) void pack_tables(const float* __restrict__ X,
                                                   const float* __restrict__ Eemb,
                                                   const float* __restrict__ W_nb,
                                                   const float* __restrict__ W1,
                                                   u16* __restrict__ XE,
                                                   u16* __restrict__ WnbTh,
                                                   u16* __restrict__ W1h) {
    const int XN = N_NODES * DIM;            // 4194304
    const int EE = 128 * DIM;                // 32768
    const int WE = D2 * DIM;                 // 131072
    const int WE1 = 64 * DIM;                // 16384
    const int TOT = XN + EE + WE + WE1;
    for (int i = blockIdx.x * 256 + threadIdx.x; i < TOT; i += gridDim.x * 256) {
        if (i < XN) {
            XE[i] = f2bf(X[i]);
        } else if (i < XN + EE) {
            XE[i] = f2bf(Eemb[i - XN]);      // Eemb rows appended
        } else if (i < XN + EE + WE) {
            int j = i - XN - EE;             // j = n*512 + k
            int n = j >> 9, k = j & 511;
            WnbTh[j] = f2bf(W_nb[k * DIM + n]);
        } else {
            int j = i - XN - EE - WE;        // j = n*256 + k, n<64
            int n = j >> 8, k = j & 255;
            W1h[j] = f2bf(W1[k * 64 + n]);
        }
    }
}

// ---------------------------------------------------------------------------
// build_M: M = W_node @ attenW [512,256] as hi/lo bf16 split.
// b_node is softmax-invariant (constant over k) -> dropped.
// ---------------------------------------------------------------------------
__global__ __launch_bounds__(256) void build_M(const float* __restrict__ W_node,
                                               const float* __restrict__ attenW,
                                               u16* __restrict__ Mhi,
                                               u16* __restrict__ Mlo) {
    const int j = blockIdx.x;
    const int d = threadIdx.x;
    float acc = 0.f;
    for (int e = 0; e < DIM; ++e)
        acc = fmaf(W_node[j * DIM + e], attenW[e * DIM + d], acc);
    u16 h = f2bf(acc);
    Mhi[j * DIM + d] = h;
    Mlo[j * DIM + d] = f2bf(acc - bf2f(h));
}

// ---------------------------------------------------------------------------
// gemm_z: Zh[16384,512] bf16 = Xh @ (Mhi+Mlo)^T.  2 MFMA products (hh + hl).
// BM=128, BN=128, BK=64, 4 waves (2x2), mfma 16x16x32 bf16.
// ---------------------------------------------------------------------------
__global__ __launch_bounds__(256, 2) void gemm_z(const u16* __restrict__ Xh,
                                                 const u16* __restrict__ Mhi,
                                                 const u16* __restrict__ Mlo,
                                                 u16* __restrict__ Zh) {
    constexpr int BM = 128, BN = 128, BK = 64;
    constexpr int Kd = DIM, Nd = D2;
    __shared__ short Ah[BM * BK], Bh[BN * BK], Bl[BN * BK];
    const int tid = threadIdx.x;
    const int m0 = blockIdx.x * BM, n0 = blockIdx.y * BN;
    const int w = tid >> 6, lane = tid & 63;
    const int wr = (w >> 1) * 64, wc = (w & 1) * 64;
    const int lrow = lane & 15, lkg = lane >> 4;

    f32x4 acc[4][4] = {};

    for (int k0 = 0; k0 < Kd; k0 += BK) {
#pragma unroll
        for (int i = 0; i < 4; ++i) {
            int idx = i * 256 + tid;                 // 1024 short8 slots
            int r = idx >> 3, c8 = (idx & 7) << 3;
            int li = lds_swz(r, c8);
            *(short8v*)&Ah[li] = *(const short8v*)&Xh[(size_t)(m0 + r) * Kd + k0 + c8];
            *(short8v*)&Bh[li] = *(const short8v*)&Mhi[(size_t)(n0 + r) * Kd + k0 + c8];
            *(short8v*)&Bl[li] = *(const short8v*)&Mlo[(size_t)(n0 + r) * Kd + k0 + c8];
        }
        __syncthreads();
#pragma unroll
        for (int kk = 0; kk < 2; ++kk) {
            const int kof = kk * 32 + lkg * 8;
            bf16x8 a[4], bh[4], bl[4];
#pragma unroll
            for (int i = 0; i < 4; ++i) a[i] = *(const bf16x8*)&Ah[lds_swz(wr + i * 16 + lrow, kof)];
#pragma unroll
            for (int j = 0; j < 4; ++j) {
                bh[j] = *(const bf16x8*)&Bh[lds_swz(wc + j * 16 + lrow, kof)];
                bl[j] = *(const bf16x8*)&Bl[lds_swz(wc + j * 16 + lrow, kof)];
            }
#pragma unroll
            for (int i = 0; i < 4; ++i)
#pragma unroll
                for (int j = 0; j < 4; ++j) {
                    acc[i][j] = __builtin_amdgcn_mfma_f32_16x16x32_bf16(a[i], bh[j], acc[i][j], 0, 0, 0);
                    acc[i][j] = __builtin_amdgcn_mfma_f32_16x16x32_bf16(a[i], bl[j], acc[i][j], 0, 0, 0);
                }
        }
        __syncthreads();
    }
#pragma unroll
    for (int i = 0; i < 4; ++i)
#pragma unroll
        for (int j = 0; j < 4; ++j)
#pragma unroll
            for (int r = 0; r < 4; ++r) {
                int row = m0 + wr + i * 16 + lkg * 4 + r;
                int col = n0 + wc + j * 16 + lrow;
                Zh[(size_t)row * Nd + col] = f2bf(acc[i][j][r]);
            }
}

// ---------------------------------------------------------------------------
// gather_attn: ONE WAVE PER NODE, wave-independent: no LDS, no barriers,
// no persistent stash. ALL k-loops FULLY unrolled (R6 lesson: partial unroll
// -> runtime-indexed arrays -> scratch, WRITE_SIZE 278MB). Load clustering
// bounded with sched_barrier(0) every 4 k's instead (pure motion fence,
// keeps in-flight <= 8 loads without touching register allocatability).
// XE (8.45MB) is L2/L3-resident so out-rows are re-gathered in aggregation.
// Logit reduce: in-register butterfly (lane l ends with logit[l&15]).
// REP (bf16) overwrites Zh row n in place.
// ---------------------------------------------------------------------------
__global__ __launch_bounds__(256) void gather_attn(
    const u16* __restrict__ XE,   // [16512][256] bf16 (X rows, then Eemb rows)
    const int* __restrict__ in_idx, const int* __restrict__ in_edge,
    const float* __restrict__ in_mask, const int* __restrict__ out_idx,
    const int* __restrict__ out_edge, const float* __restrict__ out_mask,
    u16* __restrict__ Zh) {
    const int tid = threadIdx.x;
    const int w = tid >> 6, lane = tid & 63;
    const int n = blockIdx.x * 4 + w;
    const int nu = __builtin_amdgcn_readfirstlane(n);

    // scalar index loads (wave-uniform address -> s_load into SGPRs)
    int oi[KNBR], noe[KNBR], ii[KNBR], nie[KNBR];
#pragma unroll
    for (int k = 0; k < KNBR; ++k) {
        oi[k] = out_idx[nu * KNBR + k];
        noe[k] = N_NODES + out_edge[nu * KNBR + k];
        ii[k] = in_idx[nu * KNBR + k];
        nie[k] = N_NODES + in_edge[nu * KNBR + k];
    }
    // per-lane mask copies (lane l holds mask[l&15])
    const float im_v = in_mask[nu * KNBR + (lane & 15)];
    const float om_v = out_mask[nu * KNBR + (lane & 15)];

    // z slice: lane l holds concat dims [8l, 8l+8)
    float zr[8];
    {
        short8v zv = *(const short8v*)&Zh[(size_t)n * D2 + lane * 8];
#pragma unroll
        for (int c = 0; c < 8; ++c) zr[c] = bf2f((u16)zv[c]);
    }

    const u32 lofs = (u32)(lane & 31) * 16u;   // byte offset within row half
    const bool lo32 = (lane < 32);
    const char* XEb = (const char*)XE;

    // Phase B: logit partials (out-rows loaded, consumed, NOT kept).
    // sched_barrier every 4 k's bounds in-flight loads to 4.
    float v[KNBR];
#pragma unroll
    for (int k = 0; k < KNBR; ++k) {
        int ro = lo32 ? oi[k] : noe[k];
        u32x4 vo = *(const u32x4*)(XEb + (((u32)ro << 9) + lofs));
        short8v sv = __builtin_bit_cast(short8v, vo);
        float q = 0.f;
#pragma unroll
        for (int c = 0; c < 8; ++c) q = fmaf(bf2f((u16)sv[c]), zr[c], q);
        v[k] = q;
        if ((k & 3) == 3) __builtin_amdgcn_sched_barrier(0);
    }

    // in-register butterfly: reduce 16 values over 64 lanes
    {
        const bool b0 = lane & 1;
#pragma unroll
        for (int i = 0; i < 8; ++i) {
            float keep = b0 ? v[2 * i + 1] : v[2 * i];
            float send = b0 ? v[2 * i] : v[2 * i + 1];
            v[i] = keep + __shfl_xor(send, 1);
        }
        const bool b1 = lane & 2;
#pragma unroll
        for (int i = 0; i < 4; ++i) {
            float keep = b1 ? v[2 * i + 1] : v[2 * i];
            float send = b1 ? v[2 * i] : v[2 * i + 1];
            v[i] = keep + __shfl_xor(send, 2);
        }
        const bool b2 = lane & 4;
#pragma unroll
        for (int i = 0; i < 2; ++i) {
            float keep = b2 ? v[2 * i + 1] : v[2 * i];
            float send = b2 ? v[2 * i] : v[2 * i + 1];
            v[i] = keep + __shfl_xor(send, 4);
        }
        const bool b3 = lane & 8;
        {
            float keep = b3 ? v[1] : v[0];
            float send = b3 ? v[0] : v[1];
            v[0] = keep + __shfl_xor(send, 8);
        }
    }
    float t = v[0];
    t += __shfl_xor(t, 16);
    t += __shfl_xor(t, 32);
    // t = logit[lane & 15] on every lane

    // softmax over the 16 k's (butterfly within 16-lane groups)
    float m = t;
#pragma unroll
    for (int d = 1; d < 16; d <<= 1) m = fmaxf(m, __shfl_xor(m, d));
    float e = __expf(t - m);
    float s = e;
#pragma unroll
    for (int d = 1; d < 16; d <<= 1) s += __shfl_xor(s, d);
    const float wt = e / s * om_v;   // lane l holds weight for k = l&15

    // aggregation: re-gather out-rows (L2-hit) + in-rows; fence every 4 k's
    // bounds in-flight to 8 loads (32 VGPRs transient).
    float acc[8] = {};
#pragma unroll
    for (int k = 0; k < KNBR; ++k) {
        int ro = lo32 ? oi[k] : noe[k];
        int ri = lo32 ? ii[k] : nie[k];
        u32x4 vo4 = *(const u32x4*)(XEb + (((u32)ro << 9) + lofs));
        u32x4 vi4 = *(const u32x4*)(XEb + (((u32)ri << 9) + lofs));
        short8v vout = __builtin_bit_cast(short8v, vo4);
        short8v vin = __builtin_bit_cast(short8v, vi4);
        float imk = __shfl(im_v, k);
        float wtk = __shfl(wt, k);
#pragma unroll
        for (int c = 0; c < 8; ++c) {
            acc[c] = fmaf(imk, bf2f((u16)vin[c]), acc[c]);
            acc[c] = fmaf(wtk, bf2f((u16)vout[c]), acc[c]);
        }
        if ((k & 3) == 3) __builtin_amdgcn_sched_barrier(0);
    }
    short8v ov;
#pragma unroll
    for (int c = 0; c < 8; ++c) ov[c] = (short)f2bf(acc[c]);
    *(short8v*)&Zh[(size_t)n * D2 + lane * 8] = ov;   // REP overlays z row
}

// ---------------------------------------------------------------------------
// gemm_h: out[16384,256] f32 = REP @ WnbTh^T + X + 2*b_nb; also writes Hh bf16
// (for the MFMA MLP). A = REP rows in Zh, pitch 512 shorts.
// ---------------------------------------------------------------------------
__global__ __launch_bounds__(256, 3) void gemm_h(const u16* __restrict__ A,
                                                 const u16* __restrict__ B,
                                                 const float* __restrict__ X,
                                                 const float* __restrict__ b_nb,
                                                 float* __restrict__ out,
                                                 u16* __restrict__ Hh) {
    constexpr int BM = 128, BN = 128, BK = 64;
    constexpr int Kd = D2, Nd = DIM;
    __shared__ short Ah[BM * BK], Bh[BN * BK];
    const int tid = threadIdx.x;
    const int m0 = blockIdx.x * BM, n0 = blockIdx.y * BN;
    const int w = tid >> 6, lane = tid & 63;
    const int wr = (w >> 1) * 64, wc = (w & 1) * 64;
    const int lrow = lane & 15, lkg = lane >> 4;

    f32x4 acc[4][4] = {};

    for (int k0 = 0; k0 < Kd; k0 += BK) {
#pragma unroll
        for (int i = 0; i < 4; ++i) {
            int idx = i * 256 + tid;
            int r = idx >> 3, c8 = (idx & 7) << 3;
            int li = lds_swz(r, c8);
            *(short8v*)&Ah[li] = *(const short8v*)&A[(size_t)(m0 + r) * Kd + k0 + c8];
            *(short8v*)&Bh[li] = *(const short8v*)&B[(size_t)(n0 + r) * Kd + k0 + c8];
        }
        __syncthreads();
#pragma unroll
        for (int kk = 0; kk < 2; ++kk) {
            const int kof = kk * 32 + lkg * 8;
            bf16x8 a[4], b[4];
#pragma unroll
            for (int i = 0; i < 4; ++i) a[i] = *(const bf16x8*)&Ah[lds_swz(wr + i * 16 + lrow, kof)];
#pragma unroll
            for (int j = 0; j < 4; ++j) b[j] = *(const bf16x8*)&Bh[lds_swz(wc + j * 16 + lrow, kof)];
#pragma unroll
            for (int i = 0; i < 4; ++i)
#pragma unroll
                for (int j = 0; j < 4; ++j)
                    acc[i][j] = __builtin_amdgcn_mfma_f32_16x16x32_bf16(a[i], b[j], acc[i][j], 0, 0, 0);
        }
        __syncthreads();
    }
#pragma unroll
    for (int i = 0; i < 4; ++i)
#pragma unroll
        for (int j = 0; j < 4; ++j)
#pragma unroll
            for (int r = 0; r < 4; ++r) {
                int row = m0 + wr + i * 16 + lkg * 4 + r;
                int col = n0 + wc + j * 16 + lrow;
                size_t off = (size_t)row * Nd + col;
                float hv = acc[i][j][r] + X[off] + 2.0f * b_nb[col];
                out[off] = hv;
                Hh[off] = f2bf(hv);
            }
}

// ---------------------------------------------------------------------------
// mlp_mfma: per block of 128 rows: T = relu(Hh @ W1h^T + b1) [128,64] (MFMA),
// column-sum over rows, dot W2 -> 2 partials per block. Deterministic.
// ---------------------------------------------------------------------------
__global__ __launch_bounds__(256) void mlp_mfma(const u16* __restrict__ Hh,
                                                const u16* __restrict__ W1h,
                                                const float* __restrict__ b1,
                                                const float* __restrict__ W2,
                                                float* __restrict__ partials) {
    constexpr int BM = 128, BN = 64, BK = 64;
    constexpr int Kd = DIM;
    __shared__ short Ah[BM * BK], Bh[BN * BK];
    __shared__ float red[4][BN];
    const int tid = threadIdx.x;
    const int m0 = blockIdx.x * BM;
    const int w = tid >> 6, lane = tid & 63;
    const int wr = w * 32;
    const int lrow = lane & 15, lkg = lane >> 4;

    f32x4 acc[2][4] = {};

    for (int k0 = 0; k0 < Kd; k0 += BK) {
#pragma unroll
        for (int i = 0; i < 4; ++i) {
            int idx = i * 256 + tid;
            int r = idx >> 3, c8 = (idx & 7) << 3;
            *(short8v*)&Ah[lds_swz(r, c8)] =
                *(const short8v*)&Hh[(size_t)(m0 + r) * Kd + k0 + c8];
        }
#pragma unroll
        for (int i = 0; i < 2; ++i) {
            int idx = i * 256 + tid;
            if (idx < 512) {
                int r = idx >> 3, c8 = (idx & 7) << 3;
                *(short8v*)&Bh[lds_swz(r, c8)] =
                    *(const short8v*)&W1h[(size_t)r * Kd + k0 + c8];
            }
        }
        __syncthreads();
#pragma unroll
        for (int kk = 0; kk < 2; ++kk) {
            const int kof = kk * 32 + lkg * 8;
            bf16x8 a[2], b[4];
#pragma unroll
            for (int i = 0; i < 2; ++i) a[i] = *(const bf16x8*)&Ah[lds_swz(wr + i * 16 + lrow, kof)];
#pragma unroll
            for (int j = 0; j < 4; ++j) b[j] = *(const bf16x8*)&Bh[lds_swz(j * 16 + lrow, kof)];
#pragma unroll
            for (int i = 0; i < 2; ++i)
#pragma unroll
                for (int j = 0; j < 4; ++j)
                    acc[i][j] = __builtin_amdgcn_mfma_f32_16x16x32_bf16(a[i], b[j], acc[i][j], 0, 0, 0);
        }
        __syncthreads();
    }
    // relu(+b1) and column-sum over this wave's 32 rows
    float cs[4];
#pragma unroll
    for (int j = 0; j < 4; ++j) {
        const float bj = b1[j * 16 + lrow];
        float sv = 0.f;
#pragma unroll
        for (int i = 0; i < 2; ++i)
#pragma unroll
            for (int r = 0; r < 4; ++r) sv += fmaxf(acc[i][j][r] + bj, 0.f);
        cs[j] = sv;
    }
#pragma unroll
    for (int j = 0; j < 4; ++j) {
        cs[j] += __shfl_xor(cs[j], 16);
        cs[j] += __shfl_xor(cs[j], 32);
    }
    if (lkg == 0) {
#pragma unroll
        for (int j = 0; j < 4; ++j) red[w][j * 16 + lrow] = cs[j];
    }
    __syncthreads();
    if (tid < 64) {
        float t = red[0][tid] + red[1][tid] + red[2][tid] + red[3][tid];
        float h0 = t * W2[tid * 2 + 0];
        float h1 = t * W2[tid * 2 + 1];
#pragma unroll
        for (int off = 32; off > 0; off >>= 1) {
            h0 += __shfl_down(h0, off);
            h1 += __shfl_down(h1, off);
        }
        if (tid == 0) {
            partials[blockIdx.x * 2 + 0] = h0;
            partials[blockIdx.x * 2 + 1] = h1;
        }
    }
}

__global__ void finalize(const float* __restrict__ partials,
                         const float* __restrict__ b2, float* __restrict__ out) {
    const int l = threadIdx.x;
    float h0 = 0.f, h1 = 0.f;
    for (int i = l; i < 128; i += 64) {
        h0 += partials[2 * i + 0];
        h1 += partials[2 * i + 1];
    }
#pragma unroll
    for (int off = 32; off > 0; off >>= 1) {
        h0 += __shfl_down(h0, off);
        h1 += __shfl_down(h1, off);
    }
    if (l == 0) {
        h0 += (float)N_NODES * b2[0];
        h1 += (float)N_NODES * b2[1];
        const float m = fmaxf(h0, h1);
        const float e0 = __expf(h0 - m), e1 = __expf(h1 - m);
        out[(size_t)N_NODES * DIM + 0] = e0 / (e0 + e1);
        out[(size_t)N_NODES * DIM + 1] = e1 / (e0 + e1);
    }
}

extern "C" void kernel_launch(void* const* d_in, const int* in_sizes, int n_in,
                              void* d_out, int out_size, void* d_ws, size_t ws_size,
                              hipStream_t stream) {
    const float* X = (const float*)d_in[0];
    const int* in_idx = (const int*)d_in[1];
    const int* in_edge = (const int*)d_in[2];
    const float* in_mask = (const float*)d_in[3];
    const int* out_idx = (const int*)d_in[4];
    const int* out_edge = (const int*)d_in[5];
    const float* out_mask = (const float*)d_in[6];
    const float* Eemb = (const float*)d_in[7];
    const float* W_nb = (const float*)d_in[8];
    const float* b_nb = (const float*)d_in[9];
    const float* W_node = (const float*)d_in[10];
    // d_in[11] = b_node: softmax-invariant -> unused
    const float* attenW = (const float*)d_in[12];
    const float* W1 = (const float*)d_in[13];
    const float* b1 = (const float*)d_in[14];
    const float* W2 = (const float*)d_in[15];
    const float* b2 = (const float*)d_in[16];
    float* out = (float*)d_out;

    char* ws = (char*)d_ws;
    u16* Zh = (u16*)ws;                         // 16 MiB (REP overlays)
    u16* XE = (u16*)(ws + 16777216);            // 8.06 MiB
    u16* Mhi = (u16*)(ws + 25231360);           // 256 KiB
    u16* Mlo = (u16*)(ws + 25493504);           // 256 KiB
    u16* WnbTh = (u16*)(ws + 25755648);         // 256 KiB
    u16* W1h = (u16*)(ws + 26017792);           // 32 KiB
    u16* Hh = (u16*)(ws + 26050560);            // 8 MiB
    float* partials = (float*)(ws + 34439168);  // 1 KiB

    pack_tables<<<2048, 256, 0, stream>>>(X, Eemb, W_nb, W1, XE, WnbTh, W1h);
    build_M<<<512, 256, 0, stream>>>(W_node, attenW, Mhi, Mlo);
    gemm_z<<<dim3(128, 4), 256, 0, stream>>>(XE, Mhi, Mlo, Zh);
    gather_attn<<<N_NODES / 4, 256, 0, stream>>>(XE, in_idx, in_edge, in_mask,
                                                 out_idx, out_edge, out_mask, Zh);
    gemm_h<<<dim3(128, 2), 256, 0, stream>>>(Zh, WnbTh, X, b_nb, out, Hh);
    mlp_mfma<<<N_NODES / 128, 256, 0, stream>>>(Hh, W1h, b1, W2, partials);
    finalize<<<1, 64, 0, stream>>>(partials, b2, out);
}